// Round 5
// baseline (756.154 us; speedup 1.0000x reference)
//
#include <hip/hip_runtime.h>
#include <hip/hip_fp16.h>
#include <hip/hip_cooperative_groups.h>
#include <stdint.h>

namespace cg = cooperative_groups;

#define Q_MAX 127.0f
#define EPSQ  1e-5f

typedef int   v4i __attribute__((ext_vector_type(4)));
typedef float v4f __attribute__((ext_vector_type(4)));

__device__ __forceinline__ int pack4i(int a, int b, int c, int d) {
    return (a & 0xff) | ((b & 0xff) << 8) | ((c & 0xff) << 16) | (d << 24);
}
// reference epilogue: fp16(acc*sm*scw) + fp16(bias), computed in fp16, returned as f32
__device__ __forceinline__ float ep(float v, float b) {
    return __half2float(__hadd(__float2half(v), __float2half(b)));
}
__device__ __forceinline__ void async16(const void* g, const void* l) {
    __builtin_amdgcn_global_load_lds((const __attribute__((address_space(1))) uint32_t*)g,
                                     (__attribute__((address_space(3))) uint32_t*)l,
                                     16, 0, 0);
}
// end-of-iter pipeline barrier: drain this iter's global_load_lds, sync waves.
// Raw s_barrier (NOT __syncthreads) + memory-clobber fences so the compiler can't
// hoist next iter's ds_reads above it or sink the async16s below it.
__device__ __forceinline__ void pipe_barrier() {
    asm volatile("s_waitcnt vmcnt(0)" ::: "memory");
    __builtin_amdgcn_s_barrier();
    asm volatile("" ::: "memory");
}

// ================= cooperative single-dispatch fast path =========================
// Phase A: pack w32->w8 (45MB) + quant x->xq (16MB) once.  grid.sync().
// Phase B: int8 GEMM, 2-phase double-buffered async16 pipeline, bn-major L2 order.
// Pure per call: every ws byte read in phase B is written in phase A of the SAME call.
#define BMc 128
#define BNc 128
#define BKc 64
#define CTHR 256
#define CGRID 1024

__global__ __launch_bounds__(CTHR, 4) void w8a8_coop(const float* __restrict__ x,
                                                     const int* __restrict__ w32,
                                                     const float* __restrict__ scw,
                                                     const float* __restrict__ bias,
                                                     float* __restrict__ out,
                                                     int8_t* __restrict__ w8,
                                                     int8_t* __restrict__ xq,
                                                     float* __restrict__ scales,
                                                     int M, int N, int K) {
    __shared__ __align__(16) int8_t As[2][BMc * BKc];   // 2 x 8 KB
    __shared__ __align__(16) int8_t Bs[2][BNc * BKc];   // 2 x 8 KB

    const int t   = threadIdx.x;
    const int bid = blockIdx.x;
    const int w   = t >> 6;
    const int l   = t & 63;

    // ---- phase A1: w32 -> w8, fully coalesced (int4 in -> int word out), nt stream
    {
        const int T   = CGRID * CTHR;
        const int tg  = bid * CTHR + t;
        const v4i* src = (const v4i*)w32;
        int* dst = (int*)w8;
        const int tot = (N * K) >> 2;
#pragma unroll 4
        for (int h = tg; h < tot; h += T) {
            v4i u = __builtin_nontemporal_load(src + h);   // single-use stream
            dst[h] = pack4i(u[0], u[1], u[2], u[3]);
        }
    }
    // ---- phase A2: per-row absmax + quantize, one wave per row (4 rows/block)
    {
        const int row = bid * 4 + w;
        if (row < M) {
            const v4f* p = (const v4f*)(x + (size_t)row * K);
            const int npl = K / 256;                       // v4f per lane
            float amax = 0.f;
            for (int i = 0; i < npl; ++i) {
                v4f v = p[l + 64 * i];
                amax = fmaxf(amax, fmaxf(fmaxf(fabsf(v[0]), fabsf(v[1])),
                                         fmaxf(fabsf(v[2]), fabsf(v[3]))));
            }
#pragma unroll
            for (int off = 32; off >= 1; off >>= 1) amax = fmaxf(amax, __shfl_xor(amax, off));
            const float s  = fmaxf(amax, EPSQ) / Q_MAX;    // matches reference scale exactly
            const float rsc = 1.0f / s;
            if (l == 0) scales[row] = s;
            int* q4 = (int*)(xq + (size_t)row * K);
            for (int i = 0; i < npl; ++i) {
                v4f v = p[l + 64 * i];                     // second pass: cache-hot
                q4[l + 64 * i] = pack4i(__float2int_rn(v[0] * rsc), __float2int_rn(v[1] * rsc),
                                        __float2int_rn(v[2] * rsc), __float2int_rn(v[3] * rsc));
            }
        }
    }
    __threadfence();          // device-scope release before cross-XCD reads
    cg::this_grid().sync();

    // ---- phase B: GEMM ----
    const int wm = w & 1;
    const int wn = w >> 1;

    // staging map: wave w stages rows w*32+{0..15} and +16; XOR k-chunk swizzle
    const int rA0 = w * 32 + (l >> 2);
    const int rA1 = rA0 + 16;
    const int cq0 = (l & 3) ^ ((rA0 >> 1) & 3);
    const int cq1 = (l & 3) ^ ((rA1 >> 1) & 3);

    // fragment reads: m/n = lane&15, logical k-chunk q = lane>>4 at physical q^((fr>>1)&3)
    const int fr   = l & 15;
    const int fc   = (l >> 4) ^ ((fr >> 1) & 3);
    const int aoff = (wm * 64 + fr) * 64 + fc * 16;
    const int boff = (wn * 64 + fr) * 64 + fc * 16;

    const int nbm  = M / BMc;               // 32
    const int nbn  = N / BNc;               // 86
    const int nblk = nbm * nbn;             // 2752

    for (int sidx = bid; sidx < nblk; sidx += gridDim.x) {
        int L = sidx;
        if ((nblk & 7) == 0) L = (sidx & 7) * (nblk >> 3) + (sidx >> 3);  // XCD-chunked
        // bn-major within chunk: bm varies fastest -> the 512KB w8 B-panel stays in
        // this XCD's L2 for 32 consecutive tiles; xq (16MB total) streams from L3.
        const int bm = (L % nbm) * BMc;
        const int bn = (L / nbm) * BNc;

        const int8_t* gA0 = xq + (size_t)(bm + rA0) * K + cq0 * 16;
        const int8_t* gA1 = xq + (size_t)(bm + rA1) * K + cq1 * 16;
        const int8_t* gB0 = w8 + (size_t)(bn + rA0) * K + cq0 * 16;
        const int8_t* gB1 = w8 + (size_t)(bn + rA1) * K + cq1 * 16;

        auto stage = [&](int buf, int kt) {
            async16(gA0 + kt, As[buf] + w * 2048);
            async16(gA1 + kt, As[buf] + w * 2048 + 1024);
            async16(gB0 + kt, Bs[buf] + w * 2048);
            async16(gB1 + kt, Bs[buf] + w * 2048 + 1024);
        };

        v4i acc[4][4] = {};

        stage(0, 0);
        pipe_barrier();

        int cur = 0;
#pragma unroll 1
        for (int kt = 0; kt < K; kt += BKc) {
            if (kt + BKc < K) stage(cur ^ 1, kt + BKc);   // next tile in flight under compute

            v4i a[4], b[4];
#pragma unroll
            for (int i = 0; i < 4; ++i) a[i] = *(const v4i*)(As[cur] + aoff + i * 16 * 64);
#pragma unroll
            for (int j = 0; j < 4; ++j) b[j] = *(const v4i*)(Bs[cur] + boff + j * 16 * 64);
            __builtin_amdgcn_s_setprio(1);
#pragma unroll
            for (int i = 0; i < 4; ++i)
#pragma unroll
                for (int j = 0; j < 4; ++j)
                    acc[i][j] = __builtin_amdgcn_mfma_i32_16x16x64_i8(a[i], b[j], acc[i][j], 0, 0, 0);
            __builtin_amdgcn_s_setprio(0);

            pipe_barrier();                               // drain stage; readers done; swap
            cur ^= 1;
        }

        // epilogue: C/D layout col=lane&15, row=(lane>>4)*4+reg; nt stores (write-once)
        const int colb = bn + wn * 64 + fr;
#pragma unroll
        for (int i = 0; i < 4; ++i) {
            const int m0 = bm + wm * 64 + i * 16 + (l >> 4) * 4;
#pragma unroll
            for (int r = 0; r < 4; ++r) {
                const float sm = scales[m0 + r];
                float* orow = out + (size_t)(m0 + r) * N;
#pragma unroll
                for (int j = 0; j < 4; ++j) {
                    const int n = colb + j * 16;
                    __builtin_nontemporal_store(ep((float)acc[i][j][r] * sm * scw[n], bias[n]), orow + n);
                }
            }
        }
    }
}

// ================= v2 fallback: self-contained, zero-workspace (proven pass) ======
#define BM 128
#define BN 256
#define BK 64
#define NTHR 512

__global__ __launch_bounds__(NTHR) void w8a8_one(const float* __restrict__ x,
                                                 const int* __restrict__ w32,
                                                 const float* __restrict__ scw,
                                                 const float* __restrict__ bias,
                                                 float* __restrict__ out,
                                                 int M, int N, int K) {
    __shared__ __align__(16) int8_t As[2][BM * BK];
    __shared__ __align__(16) int8_t Bs[2][BN * BK];
    __shared__ float sS[BM];
    __shared__ float sR[BM];

    const int t  = threadIdx.x;
    const int w  = t >> 6;
    const int l  = t & 63;
    const int wm = w & 1;
    const int wn = w >> 1;

    const int nbn  = N / BN;
    const int nblk = (M / BM) * nbn;
    int L = blockIdx.x;
    if ((nblk & 7) == 0) {
        const int c = nblk >> 3;
        L = (L & 7) * c + (L >> 3);
    }
    const int bm = (L / nbn) * BM;
    const int bn = (L % nbn) * BN;

    {
        const int row = t >> 2;
        const int seg = t & 3;
        const float4* p = (const float4*)(x + (size_t)(bm + row) * K) + seg;
        float amax = 0.f;
        for (int j = 0; j < K / 16; ++j) {
            float4 v = p[j * 4];
            amax = fmaxf(amax, fmaxf(fmaxf(fabsf(v.x), fabsf(v.y)),
                                     fmaxf(fabsf(v.z), fabsf(v.w))));
        }
        amax = fmaxf(amax, __shfl_xor(amax, 1));
        amax = fmaxf(amax, __shfl_xor(amax, 2));
        if (seg == 0) {
            const float s = fmaxf(amax, EPSQ) / Q_MAX;
            sS[row] = s;
            sR[row] = 1.0f / s;
        }
    }
    __syncthreads();

    const int ra  = t >> 2;
    const int sa  = t & 3;
    const float rs = sR[ra];
    const float4* gA = (const float4*)(x + (size_t)(bm + ra) * K) + sa * 4;
    const int offA = ra * 64 + ((sa ^ ((ra >> 1) & 3)) << 4);

    const int rb  = t >> 1;
    const int hb  = t & 1;
    const int swb = (rb >> 1) & 3;
    const int* gB = w32 + (size_t)(bn + rb) * K + hb * 32;
    const int offB0 = rb * 64 + ((((hb * 2)    ) ^ swb) << 4);
    const int offB1 = rb * 64 + ((((hb * 2) + 1) ^ swb) << 4);

    const int fr   = l & 15;
    const int fc   = (l >> 4) ^ ((fr >> 1) & 3);
    const int aoff = (wm * 64 + fr) * 64 + fc * 16;
    const int boff = (wn * 64 + fr) * 64 + fc * 16;

    v4i acc[4][4] = {};
    float4 rA[4];
    v4i    rB[8];

    auto load_tile = [&](int kt) {
#pragma unroll
        for (int i = 0; i < 4; ++i) rA[i] = gA[(kt >> 2) + i];
        const v4i* g4 = (const v4i*)(gB + kt);
#pragma unroll
        for (int i = 0; i < 8; ++i) rB[i] = g4[i];
    };
    auto pack_write = [&](int buf) {
        const float* vals = (const float*)rA;
        int q[16];
#pragma unroll
        for (int i = 0; i < 16; ++i) q[i] = __float2int_rn(vals[i] * rs);
        int pk[4];
#pragma unroll
        for (int c2 = 0; c2 < 4; ++c2)
            pk[c2] = pack4i(q[c2 * 4 + 0], q[c2 * 4 + 1], q[c2 * 4 + 2], q[c2 * 4 + 3]);
        *(int4*)(As[buf] + offA) = *(const int4*)pk;
        int p0[4] = { pack4i(rB[0][0],rB[0][1],rB[0][2],rB[0][3]),
                      pack4i(rB[1][0],rB[1][1],rB[1][2],rB[1][3]),
                      pack4i(rB[2][0],rB[2][1],rB[2][2],rB[2][3]),
                      pack4i(rB[3][0],rB[3][1],rB[3][2],rB[3][3]) };
        int p1[4] = { pack4i(rB[4][0],rB[4][1],rB[4][2],rB[4][3]),
                      pack4i(rB[5][0],rB[5][1],rB[5][2],rB[5][3]),
                      pack4i(rB[6][0],rB[6][1],rB[6][2],rB[6][3]),
                      pack4i(rB[7][0],rB[7][1],rB[7][2],rB[7][3]) };
        *(int4*)(Bs[buf] + offB0) = *(const int4*)p0;
        *(int4*)(Bs[buf] + offB1) = *(const int4*)p1;
    };

    load_tile(0);
    pack_write(0);

    int cur = 0;
#pragma unroll 1
    for (int kt = 0; kt < K; kt += BK) {
        __syncthreads();
        const bool more = (kt + BK) < K;
        if (more) load_tile(kt + BK);

        const int8_t* Ab = As[cur];
        const int8_t* Bb = Bs[cur];
        v4i a[4], b[4];
#pragma unroll
        for (int i = 0; i < 4; ++i) a[i] = *(const v4i*)(Ab + aoff + i * 16 * 64);
#pragma unroll
        for (int j = 0; j < 4; ++j) b[j] = *(const v4i*)(Bb + boff + j * 16 * 64);
#pragma unroll
        for (int i = 0; i < 4; ++i)
#pragma unroll
            for (int j = 0; j < 4; ++j)
                acc[i][j] = __builtin_amdgcn_mfma_i32_16x16x64_i8(a[i], b[j], acc[i][j], 0, 0, 0);

        __syncthreads();
        if (more) pack_write(cur ^ 1);
        cur ^= 1;
    }

    const int colb = bn + wn * 64 + fr;
#pragma unroll
    for (int i = 0; i < 4; ++i) {
        const int r0 = wm * 64 + i * 16 + (l >> 4) * 4;
#pragma unroll
        for (int r = 0; r < 4; ++r) {
            const float sm = sS[r0 + r];
            float* orow = out + (size_t)(bm + r0 + r) * N;
#pragma unroll
            for (int j = 0; j < 4; ++j) {
                const int n = colb + j * 16;
                __builtin_nontemporal_store(ep((float)acc[i][j][r] * sm * scw[n], bias[n]), orow + n);
            }
        }
    }
}

extern "C" void kernel_launch(void* const* d_in, const int* in_sizes, int n_in,
                              void* d_out, int out_size, void* d_ws, size_t ws_size,
                              hipStream_t stream) {
    const float* x    = (const float*)d_in[0];   // f32 (fp16 reference values)
    const int*   wgt  = (const int*)d_in[1];     // int32 (int8 values)
    const float* scw  = (const float*)d_in[2];
    const float* bias = (const float*)d_in[3];   // f32 (fp16 reference values)
    float* out = (float*)d_out;                  // f32 output

    int N = in_sizes[2];                         // 11008
    int K = in_sizes[1] / N;                     // 4096
    int M = in_sizes[0] / K;                     // 4096

    const size_t need = (size_t)N * K + (size_t)M * K + (size_t)M * 4;
    bool done = false;
    if (ws_size >= need && (M % BMc) == 0 && (N % BNc) == 0 && (K % 256) == 0 &&
        M <= CGRID * 4) {
        int8_t* w8     = (int8_t*)d_ws;
        int8_t* xq     = w8 + (size_t)N * K;
        float*  scales = (float*)(xq + (size_t)M * K);
        void* args[] = { (void*)&x, (void*)&wgt, (void*)&scw, (void*)&bias, (void*)&out,
                         (void*)&w8, (void*)&xq, (void*)&scales,
                         (void*)&M, (void*)&N, (void*)&K };
        hipError_t err = hipLaunchCooperativeKernel((const void*)w8a8_coop,
                                                    dim3(CGRID), dim3(CTHR),
                                                    args, 0, stream);
        done = (err == hipSuccess);
    }
    if (!done) {
        const int nblk = (M / BM) * (N / BN);    // 1376
        w8a8_one<<<dim3(nblk), NTHR, 0, stream>>>(x, wgt, scw, bias, out, M, N, K);
    }
}